// Round 6
// baseline (435.195 us; speedup 1.0000x reference)
//
#include <hip/hip_runtime.h>

constexpr int N = 50000;    // nodes
constexpr int E = 800000;   // edges
constexpr int NPAD = 50048; // padded to 64-row multiple for GEMM A tiles
constexpr int NB = (N + 255) / 256;   // 196 scan blocks

typedef _Float16 half8 __attribute__((ext_vector_type(8)));
typedef _Float16 half4v __attribute__((ext_vector_type(4)));
typedef float float4v __attribute__((ext_vector_type(4)));

// ---------------- degree / normalization / CSR ----------------
__global__ __launch_bounds__(256) void deg_kernel(const int* __restrict__ dst,
                                                  int* __restrict__ degI) {
    int e = blockIdx.x * 256 + threadIdx.x;
    if (e < E) atomicAdd(&degI[dst[e]], 1);
}

__global__ __launch_bounds__(256) void dinv_kernel(const int* __restrict__ degI,
                                                   float* __restrict__ dinv) {
    int v = blockIdx.x * 256 + threadIdx.x;
    if (v < N) dinv[v] = rsqrtf((float)degI[v] + 1.0f);   // +1 = self loop
}

// ---- 3-phase scan ----
__global__ __launch_bounds__(256) void scan1_kernel(const int* __restrict__ degI,
                                                    int* __restrict__ incl,
                                                    int* __restrict__ blockSums) {
    __shared__ int s[256];
    int t = threadIdx.x;
    int i = blockIdx.x * 256 + t;
    int d = (i < N) ? degI[i] : 0;
    s[t] = d;
    __syncthreads();
    for (int off = 1; off < 256; off <<= 1) {
        int v = s[t];
        int u = (t >= off) ? s[t - off] : 0;
        __syncthreads();
        s[t] = v + u;
        __syncthreads();
    }
    if (i < N) incl[i] = s[t];
    if (t == 255) blockSums[blockIdx.x] = s[255];
}

__global__ __launch_bounds__(256) void scan2_kernel(int* __restrict__ blockSums) {
    __shared__ int s[256];
    int t = threadIdx.x;
    int v = (t < NB) ? blockSums[t] : 0;
    s[t] = v;
    __syncthreads();
    for (int off = 1; off < 256; off <<= 1) {
        int a = s[t];
        int u = (t >= off) ? s[t - off] : 0;
        __syncthreads();
        s[t] = a + u;
        __syncthreads();
    }
    if (t < NB) blockSums[t] = s[t] - v;   // exclusive block offset
}

__global__ __launch_bounds__(256) void scan3_kernel(const int* __restrict__ degI,
                                                    const int* __restrict__ incl,
                                                    const int* __restrict__ blockSums,
                                                    int* __restrict__ rowptr,
                                                    int* __restrict__ cursor) {
    int i = blockIdx.x * 256 + threadIdx.x;
    if (i < N) {
        int e = blockSums[blockIdx.x] + incl[i] - degI[i];
        rowptr[i] = e;
        cursor[i] = e;
    }
    if (i == 0) rowptr[N] = E;
}

__global__ __launch_bounds__(256) void fill_kernel(const int* __restrict__ src,
                                                   const int* __restrict__ dst,
                                                   int* __restrict__ cursor,
                                                   int* __restrict__ eidx) {
    int e = blockIdx.x * 256 + threadIdx.x;
    if (e >= E) return;
    int d = dst[e];
    int pos = atomicAdd(&cursor[d], 1);
    eidx[pos] = src[e];
}

// ---------------- weight transpose+cast: Wt[n][k] = (f16) W[k][n] ----------------
template <int K>
__global__ __launch_bounds__(256) void wt_kernel(const float* __restrict__ W,
                                                 _Float16* __restrict__ Wt) {
    int idx = blockIdx.x * 256 + threadIdx.x;
    int k = idx & (K - 1);
    int n = idx >> (K == 128 ? 7 : 8);
    Wt[idx] = (_Float16)W[(size_t)k * 256 + n];
}

// ---------------- prescale: px = dinv[v] * x   (fp32 -> fp16, 128 ch) ----------------
__global__ __launch_bounds__(256) void prescale_kernel(const float4* __restrict__ x,
                                                       const float* __restrict__ dinv,
                                                       half4v* __restrict__ px) {
    int idx = blockIdx.x * 256 + threadIdx.x;
    if (idx >= N * 32) return;
    float dv = dinv[idx >> 5];
    float4 t = x[idx];
    half4v o;
    o[0] = (_Float16)(t.x * dv);
    o[1] = (_Float16)(t.y * dv);
    o[2] = (_Float16)(t.z * dv);
    o[3] = (_Float16)(t.w * dv);
    px[idx] = o;
}

// ---------------- XCD-sliced gather-aggregate (fp16 rows, fp32 accum) ----------------
// Slice s = blockIdx.x % SLICES handles channels [s*32, s*32+32).
// Round-robin block->XCD dispatch pins slice s to one XCD (pair), whose 4 MB L2
// then holds the whole 3.2 MB slice of f -> gather re-reads become L2 hits.
// U = 8 half4v units (32 ch) per node-slice; 32 nodes per 256-thread block.
template <int C4TOT, int SLICES>
__global__ __launch_bounds__(256) void aggregate_sliced(
    const int* __restrict__ rowptr, const int* __restrict__ eidx,
    const half4v* __restrict__ f, const float* __restrict__ dinv,
    half4v* __restrict__ q) {
    constexpr int U = 8;
    int s = blockIdx.x & (SLICES - 1);
    int g = blockIdx.x / SLICES;
    int v = g * 32 + threadIdx.x / U;
    if (v >= N) return;
    int lane = threadIdx.x & (U - 1);
    size_t coff = (size_t)s * U + lane;

    int beg = rowptr[v];
    int end = rowptr[v + 1];

    half4v sv = f[(size_t)v * C4TOT + coff];   // self loop
    float a0 = (float)sv[0], a1 = (float)sv[1], a2 = (float)sv[2], a3 = (float)sv[3];

    int i = beg;
    for (; i + 1 < end; i += 2) {
        int s0 = eidx[i], s1 = eidx[i + 1];
        half4v t0 = f[(size_t)s0 * C4TOT + coff];
        half4v t1 = f[(size_t)s1 * C4TOT + coff];
        a0 += (float)t0[0] + (float)t1[0];
        a1 += (float)t0[1] + (float)t1[1];
        a2 += (float)t0[2] + (float)t1[2];
        a3 += (float)t0[3] + (float)t1[3];
    }
    if (i < end) {
        half4v t0 = f[(size_t)eidx[i] * C4TOT + coff];
        a0 += (float)t0[0];
        a1 += (float)t0[1];
        a2 += (float)t0[2];
        a3 += (float)t0[3];
    }

    float dv = dinv[v];
    half4v o;
    o[0] = (_Float16)(a0 * dv);
    o[1] = (_Float16)(a1 * dv);
    o[2] = (_Float16)(a2 * dv);
    o[3] = (_Float16)(a3 * dv);
    q[(size_t)v * C4TOT + coff] = o;
}

// ---------------- fp16 MFMA GEMM, no LDS ----------------
template <int K, bool FUSE1>
__global__ __launch_bounds__(256) void gemm_mfma(
    const _Float16* __restrict__ A, const _Float16* __restrict__ Wt,
    const float* __restrict__ bias, const float* __restrict__ dinv,
    void* __restrict__ outp) {
    int wave = threadIdx.x >> 6;
    int lane = threadIdx.x & 63;
    int m = lane & 15;
    int quad = lane >> 4;
    int rbase = blockIdx.x * 64 + wave * 16;
    int cbase = blockIdx.y * 64;

    float4v acc[4] = {};

    const half8* Arow = (const half8*)(A + (size_t)(rbase + m) * K);
#pragma unroll
    for (int k0 = 0; k0 < K; k0 += 32) {
        half8 a = Arow[(k0 >> 3) + quad];
#pragma unroll
        for (int c = 0; c < 4; ++c) {
            const half8* Brow = (const half8*)(Wt + (size_t)(cbase + c * 16 + m) * K);
            half8 b = Brow[(k0 >> 3) + quad];
            acc[c] = __builtin_amdgcn_mfma_f32_16x16x32_f16(a, b, acc[c], 0, 0, 0);
        }
    }

#pragma unroll
    for (int c = 0; c < 4; ++c) {
        int col = cbase + c * 16 + m;
        float bcol = bias[col];
#pragma unroll
        for (int r = 0; r < 4; ++r) {
            int row = rbase + quad * 4 + r;   // C/D: col=lane&15, row=quad*4+reg
            if (row < N) {
                float val = acc[c][r] + bcol;
                if (FUSE1) {
                    val = fmaxf(val, 0.f) * dinv[row];
                    ((_Float16*)outp)[(size_t)row * 256 + col] = (_Float16)val;
                } else {
                    ((float*)outp)[(size_t)row * 256 + col] = val;
                }
            }
        }
    }
}

extern "C" void kernel_launch(void* const* d_in, const int* in_sizes, int n_in,
                              void* d_out, int out_size, void* d_ws, size_t ws_size,
                              hipStream_t stream) {
    const float* x  = (const float*)d_in[0];
    const int* edge = (const int*)d_in[1];
    const int* src  = edge;
    const int* dst  = edge + E;
    const float* W1 = (const float*)d_in[2];
    const float* b1 = (const float*)d_in[3];
    const float* W2 = (const float*)d_in[4];
    const float* b2 = (const float*)d_in[5];
    float* out = (float*)d_out;

    _Float16* bufA = (_Float16*)d_ws;
    _Float16* bufB = bufA + (size_t)NPAD * 256;
    float* dinv    = (float*)(bufB + (size_t)NPAD * 256);
    int* degI      = (int*)(dinv + N);
    int* rowptr    = degI + N;
    int* cursor    = rowptr + (N + 1);
    int* eidx      = cursor + N;
    _Float16* W1t  = (_Float16*)(eidx + E);
    _Float16* W2t  = W1t + 256 * 128;
    int* blockSums = (int*)(W2t + 256 * 256);

    // ---- CSR + normalization ----
    hipMemsetAsync(degI, 0, N * sizeof(int), stream);
    deg_kernel<<<(E + 255) / 256, 256, 0, stream>>>(dst, degI);
    dinv_kernel<<<(N + 255) / 256, 256, 0, stream>>>(degI, dinv);
    scan1_kernel<<<NB, 256, 0, stream>>>(degI, cursor, blockSums);
    scan2_kernel<<<1, 256, 0, stream>>>(blockSums);
    scan3_kernel<<<NB, 256, 0, stream>>>(degI, cursor, blockSums, rowptr, cursor);
    fill_kernel<<<(E + 255) / 256, 256, 0, stream>>>(src, dst, cursor, eidx);

    // ---- weights to f16 transposed ----
    wt_kernel<128><<<(256 * 128) / 256, 256, 0, stream>>>(W1, W1t);
    wt_kernel<256><<<(256 * 256) / 256, 256, 0, stream>>>(W2, W2t);

    const int NGROUPS = (N + 31) / 32;   // 32 nodes per block

    // ---- layer 1:  q1 = Ahat x (128 ch, 4 slices), h1p = dinv*relu(q1@W1+b1) ----
    prescale_kernel<<<(N * 32 + 255) / 256, 256, 0, stream>>>(
        (const float4*)x, dinv, (half4v*)bufA);
    aggregate_sliced<32, 4><<<NGROUPS * 4, 256, 0, stream>>>(
        rowptr, eidx, (const half4v*)bufA, dinv, (half4v*)bufB);
    gemm_mfma<128, true><<<dim3(NPAD / 64, 4), 256, 0, stream>>>(
        bufB, W1t, b1, dinv, bufA);

    // ---- layer 2:  q2 = Ahat h1 (256 ch, 8 slices), out = q2@W2 + b2 ----
    aggregate_sliced<64, 8><<<NGROUPS * 8, 256, 0, stream>>>(
        rowptr, eidx, (const half4v*)bufA, dinv, (half4v*)bufB);
    gemm_mfma<256, false><<<dim3(NPAD / 64, 4), 256, 0, stream>>>(
        bufB, W2t, b2, dinv, out);
}